// Round 1
// 399.202 us; speedup vs baseline: 1.0064x; 1.0064x over previous
//
#include <hip/hip_runtime.h>
#include <cstdint>
#include <cstddef>

// Problem constants (Learnable_32650341384420)
#define HH 1024      // H (channels)
#define LL 8192      // L (sequence)
#define NB 4         // B (batch)
#define KD 64
#define KLEN 512     // KD * 2^(NS-1)

typedef float v4f  __attribute__((ext_vector_type(4)));
typedef float v16f __attribute__((ext_vector_type(16)));
typedef short v8s  __attribute__((ext_vector_type(8)));

__device__ __forceinline__ unsigned short f2bf(float f) {
  union { float f; unsigned int u; } x; x.f = f;
  unsigned int r = x.u + 0x7fffu + ((x.u >> 16) & 1u);
  return (unsigned short)(r >> 16);
}

// ---------------------------------------------------------------------------
// K1: build normalized 512-tap kernel per h (fp32).
// ---------------------------------------------------------------------------
__global__ __launch_bounds__(512) void build_k_kernel(
    const float* __restrict__ k0, const float* __restrict__ k1,
    const float* __restrict__ k2, const float* __restrict__ k3,
    float* __restrict__ kout) {
  __shared__ float lk[4][KD];
  __shared__ float red[512];
  const int h = blockIdx.x;
  const int t = threadIdx.x;
  if (t < 256) {
    int i = t >> 6, j = t & 63;
    const float* src = (i == 0) ? k0 : (i == 1) ? k1 : (i == 2) ? k2 : k3;
    lk[i][j] = src[h * KD + j];
  }
  __syncthreads();
  float kt = 0.f;
#pragma unroll
  for (int i = 0; i < 4; i++) {
    int len = KD << i;
    if (t < len) {
      float inv = 1.0f / (float)(1 << i);
      float c = ((float)t + 0.5f) * inv - 0.5f;
      c = fminf(fmaxf(c, 0.0f), 63.0f);
      int lo = (int)floorf(c);
      int hi = min(lo + 1, 63);
      float w = c - (float)lo;
      float v = lk[i][lo] * (1.0f - w) + lk[i][hi] * w;
      kt += v * (float)(1 << (3 - i));
    }
  }
  red[t] = kt * kt;
  __syncthreads();
  for (int s = 256; s > 0; s >>= 1) {
    if (t < s) red[t] += red[t + s];
    __syncthreads();
  }
  float norm = sqrtf(red[0]);
  kout[h * KLEN + t] = kt / norm;
}

// ---------------------------------------------------------------------------
// K2: W (fp32) -> bf16 bits
// ---------------------------------------------------------------------------
__global__ void w2bf_kernel(const float* __restrict__ W,
                            unsigned short* __restrict__ Wb, int n) {
  int i = blockIdx.x * blockDim.x + threadIdx.x;
  if (i < n) Wb[i] = f2bf(W[i]);
}

// ---------------------------------------------------------------------------
// K3: depthwise causal 512-tap FIR via block-Toeplitz MFMA (unchanged).
// Writes g bf16 [b][h][l] into workspace.
// ---------------------------------------------------------------------------
__global__ __launch_bounds__(256) void conv_kernel(
    const float* __restrict__ u, const float* __restrict__ kk,
    const float* __restrict__ D, unsigned short* __restrict__ g) {
  __shared__ __align__(16) unsigned short Apk[34 * 512];  // fragment-packed A
  __shared__ __align__(16) unsigned short su[512 + LL];   // bf16 u row, left pad
  __shared__ __align__(16) float skk[KLEN];               // fp32 k row

  const int h = blockIdx.x;
  const int tid = threadIdx.x;
  const int w = tid >> 6;
  const int ln = tid & 63;
  const int n = ln & 31;        // MFMA col (block index i)
  const int q = ln >> 5;        // k-half selector

  // stage normalized kernel row
  if (tid < 128) *(float4*)(skk + tid * 4) = *(const float4*)(kk + (size_t)h * KLEN + tid * 4);
  __syncthreads();

  // build fragment-packed Toeplitz A: Apk[s*512 + lane*8 + j] = A[m][16s+q*8+j]
#pragma unroll 4
  for (int e = 0; e < 68; ++e) {
    int idx = e * 256 + tid;
    int s = idx >> 9;
    int lane = (idx >> 3) & 63;
    int j = idx & 7;
    int m = lane & 31, q2 = lane >> 5;
    int c = ((s & 1) << 4) + (q2 << 3) + j;
    int t = ((s >> 1) << 5) + m - c;
    Apk[idx] = (t >= 0 && t < KLEN) ? f2bf(skk[t]) : (unsigned short)0;
  }

  const float Dh = D[h];
  const int b_base0 = 512 + 32 * (w * 64 + n) + 8 * q;  // tile0: i0 = 64w
  const int b_base1 = b_base0 + 1024;                   // tile1: i0 = 64w+32

  for (int b = 0; b < NB; ++b) {
    __syncthreads();  // prev-iter su readers done (and Apk built, iter 0)
    const float* __restrict__ urow = u + ((size_t)b * HH + h) * LL;
    if (tid < 64) {
      uint4 z; z.x = 0; z.y = 0; z.z = 0; z.w = 0;
      *(uint4*)(su + tid * 8) = z;
    }
#pragma unroll
    for (int r = 0; r < 8; ++r) {
      int i = r * 1024 + tid * 4;
      float4 v = *(const float4*)(urow + i);
      uint2 p;
      p.x = (unsigned)f2bf(v.x) | ((unsigned)f2bf(v.y) << 16);
      p.y = (unsigned)f2bf(v.z) | ((unsigned)f2bf(v.w) << 16);
      *(uint2*)(su + 512 + i) = p;
    }
    __syncthreads();

    v16f acc0, acc1;
#pragma unroll
    for (int r = 0; r < 16; ++r) { acc0[r] = 0.f; acc1[r] = 0.f; }

#pragma unroll
    for (int s = 0; s < 34; ++s) {
      const int off = ((s & 1) << 4) - ((s >> 1) << 5);
      v8s af = *(const v8s*)(Apk + (s << 9) + (ln << 3));
      v8s b0 = *(const v8s*)(su + b_base0 + off);
      v8s b1 = *(const v8s*)(su + b_base1 + off);
      acc0 = __builtin_amdgcn_mfma_f32_32x32x16_bf16(af, b0, acc0, 0, 0, 0);
      acc1 = __builtin_amdgcn_mfma_f32_32x32x16_bf16(af, b1, acc1, 0, 0, 0);
    }

    // epilogue: C layout col=n, row=(reg&3)+8*(reg>>2)+4*q
    unsigned short* grow = g + ((size_t)b * HH + h) * LL;
#pragma unroll
    for (int t = 0; t < 2; ++t) {
      const int i0 = w * 64 + t * 32;
#pragma unroll
      for (int rg = 0; rg < 4; ++rg) {
        const int l = 32 * (i0 + n) + 8 * rg + 4 * q;
        float4 uu = *(const float4*)(urow + l);
        const float* up = (const float*)&uu;
        unsigned short hb[4];
#pragma unroll
        for (int rr = 0; rr < 4; ++rr) {
          float y = (t ? acc1[rg * 4 + rr] : acc0[rg * 4 + rr]) + Dh * up[rr];
          float ge = 0.5f * y * (1.0f + erff(y * 0.70710678118654752f));
          hb[rr] = f2bf(ge);
        }
        uint2 p;
        p.x = (unsigned)hb[0] | ((unsigned)hb[1] << 16);
        p.y = (unsigned)hb[2] | ((unsigned)hb[3] << 16);
        *(uint2*)(grow + l) = p;
      }
    }
  }
}

// ---------------------------------------------------------------------------
// K5 (fused transpose): out[b][o][l] = sum_h W[o][h] * g[b][h][l] + bias[o]
// B-operand consumed directly from g [b][h][l]: coalesced reg loads of row
// pairs (h, h+1), packed to (k,k+1) bf16-pair u32 per l, stored to an
// XOR-swizzled [kp=16][l=128] u32 LDS tile. Fragment reads are 4x ds_read_b32
// per frag, 2-way bank aliasing (free). XCD-swizzled block mapping: each XCD
// owns 32 contiguous nt (B fetched once per tile) and reuses the 2 MB A panel.
// ---------------------------------------------------------------------------
__device__ __forceinline__ void gll16(const void* g, void* l) {
  __builtin_amdgcn_global_load_lds(
      (const __attribute__((address_space(1))) unsigned int*)g,
      (__attribute__((address_space(3))) unsigned int*)l, 16, 0, 0);
}

__global__ __launch_bounds__(256) void gemm_kernel(
    const unsigned short* __restrict__ A,   // W bf16 [1024][1024]
    const unsigned short* __restrict__ G,   // g bf16 [4][1024][8192]
    const float* __restrict__ bias, float* __restrict__ out) {
  __shared__ __align__(16) unsigned short sA[128 * 32];
  __shared__ __align__(16) unsigned int   sB[16 * 128];  // (k,k+1) pair per l
  const int tid = threadIdx.x;
  const int wv = tid >> 6, ln = tid & 63;

  // bijective XCD swizzle (2048 % 8 == 0): XCD r owns logical [r*256, r*256+256)
  // logical order is nt-major-in-chunks: nt = swz>>3, mt = swz&7 -> the 8
  // blocks sharing a B tile are consecutive logical ids on ONE XCD.
  const int bid0 = blockIdx.x;
  const int swz = (bid0 & 7) * 256 + (bid0 >> 3);
  const int mt = swz & 7, nt = swz >> 3;
  const int o0 = mt * 128;
  const int bb = nt >> 6;             // batch index
  const int l0 = (nt & 63) * 128;     // l-tile base
  const int m16 = ln & 15, q4 = ln >> 4;
  const int wm = wv & 1, wn = wv >> 1;

  v4f acc[4][4];
#pragma unroll
  for (int i = 0; i < 4; i++)
#pragma unroll
    for (int j = 0; j < 4; j++) {
      v4f z = {0.f, 0.f, 0.f, 0.f};
      acc[i][j] = z;
    }

  // A staging via global_load_lds: waves 0,1 cover 8 slots of 16 o-rows each.
  const unsigned short* gptrA[4];
  unsigned short* lptrA[4];
  if (wv < 2) {
#pragma unroll
    for (int qq = 0; qq < 4; qq++) {
      int c = wv * 4 + qq;
      int rr = c * 16 + (ln >> 2);
      int cc = (ln & 3) * 8;
      gptrA[qq] = A + (size_t)(o0 + rr) * HH + cc;
      lptrA[qq] = sA + c * 512;
    }
  }

  // B staging ids: thread -> (kp = k-pair 0..15, seg = l-octet 0..15)
  const int kp = tid >> 4;
  const int seg = tid & 15;
  char* sBb = (char*)sB;
  const unsigned xw = ((unsigned)(kp & 1) << 4) | ((unsigned)((kp >> 2) & 1) << 6);
  const unsigned wb0 = (unsigned)(kp * 512 + seg * 32);
  const unsigned short* gB0 = G + ((size_t)bb * HH + kp * 2) * LL + l0 + seg * 8;
  const unsigned short* gB1 = gB0 + LL;

  const int nloc = wn * 64 + m16;  // + j*16 per fragment column tile

  uint4 ra = *(const uint4*)(gB0);
  uint4 rb = *(const uint4*)(gB1);

  for (int kk = 0; kk < 32; kk++) {
    // ---- stage B(kk): pack (k,k+1) bf16 pairs per l, swizzled b128 writes
    union { uint4 u; unsigned short s[8]; } ua, ub;
    ua.u = ra; ub.u = rb;
    unsigned pk[8];
#pragma unroll
    for (int i = 0; i < 8; ++i)
      pk[i] = (unsigned)ua.s[i] | ((unsigned)ub.s[i] << 16);
    *(uint4*)(sBb + ((wb0)      ^ xw)) = *(const uint4*)&pk[0];
    *(uint4*)(sBb + ((wb0 + 16) ^ xw)) = *(const uint4*)&pk[4];

    // ---- stage A(kk) direct to LDS
    if (wv < 2) {
#pragma unroll
      for (int qq = 0; qq < 4; qq++) gll16(gptrA[qq] + kk * 32, lptrA[qq]);
    }
    __syncthreads();

    // ---- prefetch B regs for kk+1 (hides under MFMA phase)
    if (kk < 31) {
      ra = *(const uint4*)(gB0 + (size_t)(kk + 1) * 32 * LL);
      rb = *(const uint4*)(gB1 + (size_t)(kk + 1) * 32 * LL);
    }

    // ---- fragments
    v8s af[4];
#pragma unroll
    for (int i = 0; i < 4; i++)
      af[i] = *(const v8s*)&sA[(wm * 64 + i * 16 + m16) * 32 + q4 * 8];
    v8s bf4[4];
#pragma unroll
    for (int j = 0; j < 4; j++) {
      union { v8s v; unsigned w[4]; } u;
#pragma unroll
      for (int p = 0; p < 4; p++) {
        unsigned boff = ((unsigned)((q4 * 4 + p) * 128 + nloc + j * 16) << 2)
                        ^ ((unsigned)(p & 1) << 4) ^ ((unsigned)(q4 & 1) << 6);
        u.w[p] = *(const unsigned*)(sBb + boff);
      }
      bf4[j] = u.v;
    }
#pragma unroll
    for (int i = 0; i < 4; i++)
#pragma unroll
      for (int j = 0; j < 4; j++)
        acc[i][j] = __builtin_amdgcn_mfma_f32_16x16x32_bf16(af[i], bf4[j], acc[i][j], 0, 0, 0);
    __syncthreads();
  }

#pragma unroll
  for (int i = 0; i < 4; i++) {
    const int ob = o0 + wm * 64 + i * 16 + q4 * 4;
#pragma unroll
    for (int j = 0; j < 4; j++) {
      const int l = l0 + wn * 64 + j * 16 + m16;
#pragma unroll
      for (int r = 0; r < 4; r++) {
        const int o = ob + r;
        out[((size_t)bb * HH + o) * LL + l] = acc[i][j][r] + bias[o];
      }
    }
  }
}

// ---------------------------------------------------------------------------
extern "C" void kernel_launch(void* const* d_in, const int* in_sizes, int n_in,
                              void* d_out, int out_size, void* d_ws, size_t ws_size,
                              hipStream_t stream) {
  const float* u   = (const float*)d_in[0];
  const float* k0  = (const float*)d_in[1];
  const float* k1  = (const float*)d_in[2];
  const float* k2  = (const float*)d_in[3];
  const float* k3  = (const float*)d_in[4];
  const float* D   = (const float*)d_in[5];
  const float* W   = (const float*)d_in[6];
  const float* bia = (const float*)d_in[7];
  float* out = (float*)d_out;

  // ws layout: g bf16 (64 MiB) | k fp32 (2 MiB) | W bf16 (2 MiB)
  // g must NOT alias d_out anymore: gemm reads g while writing out.
  char* ws = (char*)d_ws;
  unsigned short* g  = (unsigned short*)ws;
  float* kws         = (float*)(ws + (size_t)67108864);
  unsigned short* Wb = (unsigned short*)(ws + (size_t)69206016);

  build_k_kernel<<<HH, 512, 0, stream>>>(k0, k1, k2, k3, kws);
  w2bf_kernel<<<(HH * HH + 255) / 256, 256, 0, stream>>>(W, Wb, HH * HH);
  conv_kernel<<<HH, 256, 0, stream>>>(u, kws, D, g);
  gemm_kernel<<<8 * 256, 256, 0, stream>>>(Wb, g, bia, out);
}